// Round 15
// baseline (76.535 us; speedup 1.0000x reference)
//
#include <hip/hip_runtime.h>
#include <hip/hip_bf16.h>
#include <hip/hip_fp8.h>

// Problem constants (fixed by setup_inputs): B=4096, d=128, M=8192, C=16
#define B_ROWS 4096
#define D_K    128
#define M_ROWS 8192
#define N_TOT  12288   // B_ROWS + M_ROWS
#define NCHUNK 32      // j-chunks (grid.x of sim), 384 cols each
#define JT_PER_CHUNK 6 // 6 tiles of 64 cols: 32*6*64 = 12288 = N_TOT (coverage!)
#define JCOLS  64      // cols per tile
#define NCLS   16
#define SIM_BLOCKS 1024
#define SVC_BLOCKS 128

typedef __attribute__((ext_vector_type(4))) int   intx4;
typedef __attribute__((ext_vector_type(8))) int   intx8;
typedef __attribute__((ext_vector_type(4))) float floatx4;

__device__ __forceinline__ float fp8_to_f32(unsigned char b) {
    __hip_fp8_e4m3 h; h.__x = b; return float(h);
}

// ---------------------------------------------------------------------------
// Kernel 1 (R13-verbatim + cnt zeroing): normalize rows into fp8 G8; in-batch
// rows also stored pre-scaled by log2(e) into A8 (exp2 epilogue). One wave
// per row. Block 0 zeros S/hist/out/cnt (ordered before launch 2).
// ---------------------------------------------------------------------------
__global__ __launch_bounds__(256) void nrm_kernel(
    const float* __restrict__ f, const float* __restrict__ fneg,
    unsigned char* __restrict__ G8, unsigned char* __restrict__ A8,
    float* __restrict__ S, int* __restrict__ hist, float* __restrict__ out,
    int* __restrict__ cnt)
{
    const int tid  = threadIdx.x;
    const int wave = tid >> 6;
    const int lane = tid & 63;
    const int row  = blockIdx.x * 4 + wave;           // grid exact: 3072*4
    if (blockIdx.x == 0) {
        #pragma unroll
        for (int k = 0; k < 8; ++k) S[tid + k * 256] = 0.f;
        if (tid < NCLS) hist[tid] = 0;
        if (tid == 0) { out[0] = 0.f; cnt[0] = 0; cnt[1] = 0; }
    }
    const float* src = (row < B_ROWS) ? (f + (size_t)row * D_K)
                                      : (fneg + (size_t)(row - B_ROWS) * D_K);
    float2 v = *reinterpret_cast<const float2*>(src + lane * 2);
    float ss = v.x * v.x + v.y * v.y;
    #pragma unroll
    for (int m = 1; m < 64; m <<= 1) ss += __shfl_xor(ss, m, 64);
    const float scale = 1.0f / fmaxf(sqrtf(ss), 1e-8f);   // 1/max(||x||, EPS)
    __hip_fp8_e4m3 q0(v.x * scale);
    __hip_fp8_e4m3 q1(v.y * scale);
    const unsigned short pk =
        (unsigned short)q0.__x | ((unsigned short)q1.__x << 8);
    *reinterpret_cast<unsigned short*>(G8 + (size_t)row * D_K + lane * 2) = pk;
    if (row < B_ROWS) {
        const float s2 = scale * 1.44269504f;             // * log2(e)
        __hip_fp8_e4m3 a0(v.x * s2);
        __hip_fp8_e4m3 a1(v.y * s2);
        const unsigned short pa =
            (unsigned short)a0.__x | ((unsigned short)a1.__x << 8);
        *reinterpret_cast<unsigned short*>(A8 + (size_t)row * D_K + lane * 2) = pa;
    }
}

// ---------------------------------------------------------------------------
// Kernel 2: sim (R13-verbatim body) + csum service blocks + in-kernel fin.
// Grid (32, 36):
//   y < 32 : sim (1024 blocks). After writing part_d: syncthreads ->
//            tid0 {threadfence; atomicAdd(cnt[0])} (release-arrive).
//   y >= 32: svc 0..127 — R13 csum port, then arrive on cnt[1], then tid0
//            SPINS until cnt[0]==1024 && cnt[1]==128 (device-scope atomic
//            reads), threadfence (acquire), syncthreads, then R13's fin body
//            (svc id = fin bid). Deadlock-free: spinners wait only on sim
//            blocks; capacity >= 1024 leaves >= 896 slots for sim to flow.
// ---------------------------------------------------------------------------
__global__ __launch_bounds__(256, 4) void sim_kernel(
    const unsigned char* __restrict__ G8, const unsigned char* __restrict__ A8,
    const int* __restrict__ labels, float* __restrict__ part_d,
    float* __restrict__ S, int* __restrict__ hist, float* __restrict__ out,
    int* __restrict__ cnt)
{
    __shared__ unsigned char Bs[2][JCOLS * D_K];   // 16KB; reused by csum

    const int tid  = threadIdx.x;
    const int wave = tid >> 6;
    const int lane = tid & 63;

    if (blockIdx.y >= 32) {        // ---- csum svc blocks + join + fin ----
        const int svc    = (blockIdx.y - 32) * NCHUNK + blockIdx.x;  // 0..127
        const int stripe = svc & 31;   // 128-row stripe
        const int dc     = svc >> 5;   // 0..3 : 32-dim chunk
        float* Sp = (float*)&Bs[0][0];            // 2KB of the 16KB Bs
        int*   lh = (int*)(Sp + NCLS * 32);       // +64B
        for (int k = tid; k < NCLS * 32; k += 256) Sp[k] = 0.f;
        if (tid < NCLS) lh[tid] = 0;
        __syncthreads();

        const int j0 = stripe * 128;
        if (dc == 0 && tid < 128) atomicAdd(&lh[labels[j0 + tid]], 1);

        const int d = tid & 31;
        const int w = tid >> 5;               // 0..7 row-walkers
        for (int jj = w; jj < 128; jj += 8) {
            const int j = j0 + jj;
            const int c = labels[j];
            atomicAdd(&Sp[c * 32 + d],
                      fp8_to_f32(G8[(size_t)j * D_K + dc * 32 + d]));
        }
        __syncthreads();
        for (int k = tid; k < NCLS * 32; k += 256)
            atomicAdd(&S[(k >> 5) * D_K + dc * 32 + (k & 31)], Sp[k]);
        if (dc == 0 && tid < NCLS) atomicAdd(&hist[tid], lh[tid]);

        // ---- arrive (csum done) + spin-join on sim & csum completion ----
        __syncthreads();
        if (tid == 0) {
            __threadfence();
            atomicAdd(&cnt[1], 1);
            while (atomicAdd(&cnt[0], 0) < SIM_BLOCKS)
                __builtin_amdgcn_s_sleep(8);
            while (atomicAdd(&cnt[1], 0) < SVC_BLOCKS)
                __builtin_amdgcn_s_sleep(8);
            __threadfence();   // acquire: invalidate caches before reads
        }
        __syncthreads();

        // ---- fin (R13-verbatim body, bid = svc) ----
        float lsum = 0.f;
        #pragma unroll 2
        for (int rr = 0; rr < 8; ++rr) {
            const int i   = (svc * 4 + wave) * 8 + rr;
            const int lab = labels[i];
            float pd = (lane < NCHUNK) ? part_d[(size_t)i * NCHUNK + lane] : 0.f;
            const unsigned char* gr = G8 + (size_t)i * D_K + lane * 2;
            const float f0 = fp8_to_f32(gr[0]);
            const float f1 = fp8_to_f32(gr[1]);
            float2 sv = *reinterpret_cast<const float2*>(S + lab * D_K + lane * 2);
            float self = f0 * f0 + f1 * f1;
            float sp   = f0 * sv.x + f1 * sv.y;
            #pragma unroll
            for (int m = 1; m < 64; m <<= 1) {
                pd   += __shfl_xor(pd, m, 64);
                self += __shfl_xor(self, m, 64);
                sp   += __shfl_xor(sp, m, 64);
            }
            if (lane == 0) {
                const float npos  = (float)(hist[lab] - 1);
                const float denom = pd - __expf(self);
                lsum += __logf(denom) - (sp - self) / npos;
            }
        }
        __shared__ float w4[4];
        if (lane == 0) w4[wave] = lsum;
        __syncthreads();
        if (tid == 0)
            atomicAdd(out, (w4[0] + w4[1] + w4[2] + w4[3]) * (1.0f / (float)B_ROWS));
        return;
    }

    // ======================= sim blocks (R13-verbatim) =====================
    const int jc = blockIdx.x;            // 0..31
    const int it = blockIdx.y;            // 0..31
    const int i0 = it * 128 + wave * 32;

    const int r16 = lane & 15;
    const int grp = lane >> 4;            // 0..3

    // resident A fragments [a] from A8 (log2e-scaled): rows i0 + a*16 + r16
    const unsigned char* Abase = A8 + (size_t)(i0 + r16) * D_K + grp * 32;
    intx8 afr[2];
    #pragma unroll
    for (int a = 0; a < 2; ++a)
        afr[a] = *reinterpret_cast<const intx8*>(Abase + (size_t)a * 16 * D_K);

    float dsum[2][4];
    #pragma unroll
    for (int a = 0; a < 2; ++a)
        #pragma unroll
        for (int r = 0; r < 4; ++r) dsum[a][r] = 0.f;

    // staging: 8KB tile, 256 thr x 16B x 2 rounds. LDS linear byte
    // p = s*4096 + tid*16 -> row = s*32 + tid/8, slot = tid&7;
    // source granule pre-swizzled: gran = slot ^ (row&7).
    int srcoff[2];
    #pragma unroll
    for (int s = 0; s < 2; ++s) {
        const int row  = s * 32 + (tid >> 3);
        const int gran = (tid & 7) ^ (row & 7);
        srcoff[s] = row * D_K + gran * 16;
    }

    intx4 streg[2];
    {   // prologue: tile 0 -> buf 0
        const unsigned char* src =
            G8 + (size_t)(jc * JT_PER_CHUNK) * JCOLS * D_K;
        #pragma unroll
        for (int s = 0; s < 2; ++s)
            streg[s] = *reinterpret_cast<const intx4*>(src + srcoff[s]);
        #pragma unroll
        for (int s = 0; s < 2; ++s)
            *reinterpret_cast<intx4*>(&Bs[0][0] + s * 4096 + tid * 16) =
                streg[s];
    }

    for (int t = 0; t < JT_PER_CHUNK; ++t) {
        const int cur = t & 1;
        __syncthreads();   // buf[cur] written & visible; buf[cur^1] reads done

        if (t + 1 < JT_PER_CHUNK) {
            const unsigned char* src =
                G8 + (size_t)(jc * JT_PER_CHUNK + t + 1) * JCOLS * D_K;
            #pragma unroll
            for (int s = 0; s < 2; ++s)
                streg[s] = *reinterpret_cast<const intx4*>(src + srcoff[s]);
        }

        floatx4 acc[2][4];
        #pragma unroll
        for (int a = 0; a < 2; ++a)
            #pragma unroll
            for (int b = 0; b < 4; ++b)
                acc[a][b] = (floatx4){0.f, 0.f, 0.f, 0.f};

        const unsigned char* base = &Bs[cur][0];
        #pragma unroll
        for (int b = 0; b < 4; ++b) {
            const int jloc = b * 16 + r16;
            const int sw   = jloc & 7;
            intx4 lo = *reinterpret_cast<const intx4*>(
                base + jloc * D_K + ((2 * grp)     ^ sw) * 16);
            intx4 hi = *reinterpret_cast<const intx4*>(
                base + jloc * D_K + ((2 * grp + 1) ^ sw) * 16);
            intx8 bfr;
            #pragma unroll
            for (int e = 0; e < 4; ++e) { bfr[e] = lo[e]; bfr[e + 4] = hi[e]; }
            #pragma unroll
            for (int a = 0; a < 2; ++a)
                acc[a][b] = __builtin_amdgcn_mfma_scale_f32_16x16x128_f8f6f4(
                    afr[a], bfr, acc[a][b], 0, 0,
                    0, 0x7F7F7F7F, 0, 0x7F7F7F7F);   // unity scales
        }

        // branch-free epilogue: acc = log2e*sim -> exp2 (native v_exp_f32)
        #pragma unroll
        for (int a = 0; a < 2; ++a)
            #pragma unroll
            for (int r = 0; r < 4; ++r) {
                float s0 = exp2f(acc[a][0][r]) + exp2f(acc[a][1][r]);
                float s1 = exp2f(acc[a][2][r]) + exp2f(acc[a][3][r]);
                dsum[a][r] += s0 + s1;
            }

        if (t + 1 < JT_PER_CHUNK) {
            #pragma unroll
            for (int s = 0; s < 2; ++s)
                *reinterpret_cast<intx4*>(
                    &Bs[cur ^ 1][0] + s * 4096 + tid * 16) = streg[s];
        }
    }

    // 16-lane (column-group) reduce
    #pragma unroll
    for (int a = 0; a < 2; ++a)
        #pragma unroll
        for (int r = 0; r < 4; ++r) {
            #pragma unroll
            for (int m = 1; m < 16; m <<= 1)
                dsum[a][r] += __shfl_xor(dsum[a][r], m, 64);
        }
    if (r16 == 0) {
        #pragma unroll
        for (int a = 0; a < 2; ++a)
            #pragma unroll
            for (int r = 0; r < 4; ++r)
                part_d[(size_t)(i0 + a * 16 + grp * 4 + r) * NCHUNK + jc] =
                    dsum[a][r];
    }

    // ---- arrive: part_d for this block complete ----
    __syncthreads();
    if (tid == 0) {
        __threadfence();
        atomicAdd(&cnt[0], 1);
    }
}

// ---------------------------------------------------------------------------
extern "C" void kernel_launch(void* const* d_in, const int* in_sizes, int n_in,
                              void* d_out, int out_size, void* d_ws, size_t ws_size,
                              hipStream_t stream) {
    const float* f      = (const float*)d_in[0];
    const float* fneg   = (const float*)d_in[1];
    const int*   labels = (const int*)d_in[2];
    float*       out    = (float*)d_out;

    char* ws = (char*)d_ws;
    // Workspace layout (bytes):
    //   G8     : 12288*128   = 1,572,864
    //   A8     : 4096*128    =   524,288
    //   part_d : 4096*32*4   =   524,288
    //   S      : 16*128*4    =     8,192
    //   hist   : 16*4 (pad to 128)
    //   cnt    : 2*4
    unsigned char* G8     = (unsigned char*)(ws);
    unsigned char* A8     = (unsigned char*)(ws + 1572864);
    float*         part_d = (float*)(ws + 1572864 + 524288);
    float*         S      = (float*)(ws + 1572864 + 524288 + 524288);
    int*           hist   = (int*)(ws + 1572864 + 524288 + 524288 + 8192);
    int*           cnt    = (int*)(ws + 1572864 + 524288 + 524288 + 8192 + 128);

    nrm_kernel<<<N_TOT / 4, 256, 0, stream>>>(f, fneg, G8, A8, S, hist, out, cnt);

    dim3 gridS(NCHUNK, 36);   // (32,36): 1024 sim + 128 csum/fin svc blocks
    sim_kernel<<<gridS, 256, 0, stream>>>(G8, A8, labels, part_d, S, hist, out, cnt);
}

// Round 16
// 37.034 us; speedup vs baseline: 2.0666x; 2.0666x over previous
//
#include <hip/hip_runtime.h>
#include <hip/hip_bf16.h>
#include <hip/hip_fp8.h>

// Problem constants (fixed by setup_inputs): B=4096, d=128, M=8192, C=16
#define B_ROWS 4096
#define D_K    128
#define M_ROWS 8192
#define N_TOT  12288   // B_ROWS + M_ROWS
#define NCHUNK 32      // j-chunks (grid.x of sim), 384 cols each
#define JT_PER_CHUNK 6 // 6 tiles of 64 cols: 32*6*64 = 12288 = N_TOT (coverage!)
#define JCOLS  64      // cols per tile
#define NCLS   16

typedef __attribute__((ext_vector_type(4))) int   intx4;
typedef __attribute__((ext_vector_type(8))) int   intx8;
typedef __attribute__((ext_vector_type(4))) float floatx4;

__device__ __forceinline__ float fp8_to_f32(unsigned char b) {
    __hip_fp8_e4m3 h; h.__x = b; return float(h);
}

// ---------------------------------------------------------------------------
// Kernel 1 (R13-verbatim): normalize rows of f / f_neg into OCP fp8-e4m3
// G8[N_TOT][128]; in-batch rows additionally stored pre-scaled by log2(e)
// into A8 (sim A operand -> exp2 epilogue). One wave per row. Block 0 zeros
// S/hist/out.
// ---------------------------------------------------------------------------
__global__ __launch_bounds__(256) void nrm_kernel(
    const float* __restrict__ f, const float* __restrict__ fneg,
    unsigned char* __restrict__ G8, unsigned char* __restrict__ A8,
    float* __restrict__ S, int* __restrict__ hist, float* __restrict__ out)
{
    const int tid  = threadIdx.x;
    const int wave = tid >> 6;
    const int lane = tid & 63;
    const int row  = blockIdx.x * 4 + wave;           // grid exact: 3072*4
    if (blockIdx.x == 0) {
        #pragma unroll
        for (int k = 0; k < 8; ++k) S[tid + k * 256] = 0.f;
        if (tid < NCLS) hist[tid] = 0;
        if (tid == 0) out[0] = 0.f;
    }
    const float* src = (row < B_ROWS) ? (f + (size_t)row * D_K)
                                      : (fneg + (size_t)(row - B_ROWS) * D_K);
    float2 v = *reinterpret_cast<const float2*>(src + lane * 2);
    float ss = v.x * v.x + v.y * v.y;
    #pragma unroll
    for (int m = 1; m < 64; m <<= 1) ss += __shfl_xor(ss, m, 64);
    const float scale = 1.0f / fmaxf(sqrtf(ss), 1e-8f);   // 1/max(||x||, EPS)
    __hip_fp8_e4m3 q0(v.x * scale);
    __hip_fp8_e4m3 q1(v.y * scale);
    const unsigned short pk =
        (unsigned short)q0.__x | ((unsigned short)q1.__x << 8);
    *reinterpret_cast<unsigned short*>(G8 + (size_t)row * D_K + lane * 2) = pk;
    if (row < B_ROWS) {
        const float s2 = scale * 1.44269504f;             // * log2(e)
        __hip_fp8_e4m3 a0(v.x * s2);
        __hip_fp8_e4m3 a1(v.y * s2);
        const unsigned short pa =
            (unsigned short)a0.__x | ((unsigned short)a1.__x << 8);
        *reinterpret_cast<unsigned short*>(A8 + (size_t)row * D_K + lane * 2) = pa;
    }
}

// ---------------------------------------------------------------------------
// Kernel 2 (R13 + conflict-free swizzle): sim + csum service blocks.
// Grid (32, 36): y<32 sim (1024 blocks), y>=32 csum svc (128 blocks).
//
// NEW LDS swizzle (from R15's measured 787K SQ_LDS_BANK_CONFLICT = 4-way):
// old gran = slot ^ (row&7) preserved granule parity within each 16-lane
// bank window -> 4 lanes/granule. New: gran = slot ^ ((row>>2)&1) — rows
// {x,x+8} of a window use even slots, {x+4,x+12} odd slots -> exactly 2
// lanes per 16B granule = the b128 floor, conflict-free. Same involution
// applied on the pre-swizzled global source and the ds_read (rule #21).
// ---------------------------------------------------------------------------
__global__ __launch_bounds__(256, 4) void sim_kernel(
    const unsigned char* __restrict__ G8, const unsigned char* __restrict__ A8,
    const int* __restrict__ labels, float* __restrict__ part_d,
    float* __restrict__ S, int* __restrict__ hist)
{
    __shared__ unsigned char Bs[2][JCOLS * D_K];   // 2 x 8KB

    const int tid = threadIdx.x;

    if (blockIdx.y >= 32) {        // ---- csum service blocks (R13-verbatim) ----
        const int svc    = (blockIdx.y - 32) * NCHUNK + blockIdx.x;  // 0..127
        const int stripe = svc & 31;   // 128-row stripe
        const int dc     = svc >> 5;   // 0..3 : 32-dim chunk
        float* Sp = (float*)&Bs[0][0];            // 2KB of the 16KB Bs
        int*   lh = (int*)(Sp + NCLS * 32);       // +64B
        for (int k = tid; k < NCLS * 32; k += 256) Sp[k] = 0.f;
        if (tid < NCLS) lh[tid] = 0;
        __syncthreads();

        const int j0 = stripe * 128;
        if (dc == 0 && tid < 128) atomicAdd(&lh[labels[j0 + tid]], 1);

        const int d = tid & 31;
        const int w = tid >> 5;               // 0..7 row-walkers
        for (int jj = w; jj < 128; jj += 8) {
            const int j = j0 + jj;
            const int c = labels[j];
            atomicAdd(&Sp[c * 32 + d],
                      fp8_to_f32(G8[(size_t)j * D_K + dc * 32 + d]));
        }
        __syncthreads();
        for (int k = tid; k < NCLS * 32; k += 256)
            atomicAdd(&S[(k >> 5) * D_K + dc * 32 + (k & 31)], Sp[k]);
        if (dc == 0 && tid < NCLS) atomicAdd(&hist[tid], lh[tid]);
        return;
    }

    const int jc   = blockIdx.x;          // 0..31
    const int it   = blockIdx.y;          // 0..31
    const int wave = tid >> 6;            // 0..3 : i-quarter
    const int lane = tid & 63;
    const int i0   = it * 128 + wave * 32;

    const int r16 = lane & 15;
    const int grp = lane >> 4;            // 0..3

    // resident A fragments [a] from A8 (log2e-scaled): rows i0 + a*16 + r16
    const unsigned char* Abase = A8 + (size_t)(i0 + r16) * D_K + grp * 32;
    intx8 afr[2];
    #pragma unroll
    for (int a = 0; a < 2; ++a)
        afr[a] = *reinterpret_cast<const intx8*>(Abase + (size_t)a * 16 * D_K);

    float dsum[2][4];
    #pragma unroll
    for (int a = 0; a < 2; ++a)
        #pragma unroll
        for (int r = 0; r < 4; ++r) dsum[a][r] = 0.f;

    // staging: 8KB tile, 256 thr x 16B x 2 rounds. LDS linear byte
    // p = s*4096 + tid*16 -> row = s*32 + tid/8, slot = tid&7;
    // source granule pre-swizzled: gran = slot ^ ((row>>2)&1)  [NEW]
    int srcoff[2];
    #pragma unroll
    for (int s = 0; s < 2; ++s) {
        const int row  = s * 32 + (tid >> 3);
        const int gran = (tid & 7) ^ ((row >> 2) & 1);
        srcoff[s] = row * D_K + gran * 16;
    }

    intx4 streg[2];
    {   // prologue: tile 0 -> buf 0
        const unsigned char* src =
            G8 + (size_t)(jc * JT_PER_CHUNK) * JCOLS * D_K;
        #pragma unroll
        for (int s = 0; s < 2; ++s)
            streg[s] = *reinterpret_cast<const intx4*>(src + srcoff[s]);
        #pragma unroll
        for (int s = 0; s < 2; ++s)
            *reinterpret_cast<intx4*>(&Bs[0][0] + s * 4096 + tid * 16) =
                streg[s];
    }

    for (int t = 0; t < JT_PER_CHUNK; ++t) {
        const int cur = t & 1;
        __syncthreads();   // buf[cur] written & visible; buf[cur^1] reads done

        if (t + 1 < JT_PER_CHUNK) {
            const unsigned char* src =
                G8 + (size_t)(jc * JT_PER_CHUNK + t + 1) * JCOLS * D_K;
            #pragma unroll
            for (int s = 0; s < 2; ++s)
                streg[s] = *reinterpret_cast<const intx4*>(src + srcoff[s]);
        }

        floatx4 acc[2][4];
        #pragma unroll
        for (int a = 0; a < 2; ++a)
            #pragma unroll
            for (int b = 0; b < 4; ++b)
                acc[a][b] = (floatx4){0.f, 0.f, 0.f, 0.f};

        const unsigned char* base = &Bs[cur][0];
        #pragma unroll
        for (int b = 0; b < 4; ++b) {
            const int jloc = b * 16 + r16;
            const int sw   = (jloc >> 2) & 1;            // [NEW] row bit 2
            intx4 lo = *reinterpret_cast<const intx4*>(
                base + jloc * D_K + ((2 * grp)     ^ sw) * 16);
            intx4 hi = *reinterpret_cast<const intx4*>(
                base + jloc * D_K + ((2 * grp + 1) ^ sw) * 16);
            intx8 bfr;
            // sw only flips granule bit0: (2g)^1 = 2g+1, (2g+1)^1 = 2g, so
            // lo/hi swap when sw==1 — reassemble in logical order.
            if (sw) { intx4 tmp = lo; lo = hi; hi = tmp; }
            #pragma unroll
            for (int e = 0; e < 4; ++e) { bfr[e] = lo[e]; bfr[e + 4] = hi[e]; }
            #pragma unroll
            for (int a = 0; a < 2; ++a)
                acc[a][b] = __builtin_amdgcn_mfma_scale_f32_16x16x128_f8f6f4(
                    afr[a], bfr, acc[a][b], 0, 0,
                    0, 0x7F7F7F7F, 0, 0x7F7F7F7F);   // unity scales
        }

        // branch-free epilogue: acc = log2e*sim -> exp2 (native v_exp_f32)
        #pragma unroll
        for (int a = 0; a < 2; ++a)
            #pragma unroll
            for (int r = 0; r < 4; ++r) {
                float s0 = exp2f(acc[a][0][r]) + exp2f(acc[a][1][r]);
                float s1 = exp2f(acc[a][2][r]) + exp2f(acc[a][3][r]);
                dsum[a][r] += s0 + s1;
            }

        if (t + 1 < JT_PER_CHUNK) {
            #pragma unroll
            for (int s = 0; s < 2; ++s)
                *reinterpret_cast<intx4*>(
                    &Bs[cur ^ 1][0] + s * 4096 + tid * 16) = streg[s];
        }
    }

    // 16-lane (column-group) reduce
    #pragma unroll
    for (int a = 0; a < 2; ++a)
        #pragma unroll
        for (int r = 0; r < 4; ++r) {
            #pragma unroll
            for (int m = 1; m < 16; m <<= 1)
                dsum[a][r] += __shfl_xor(dsum[a][r], m, 64);
        }
    if (r16 == 0) {
        #pragma unroll
        for (int a = 0; a < 2; ++a)
            #pragma unroll
            for (int r = 0; r < 4; ++r)
                part_d[(size_t)(i0 + a * 16 + grp * 4 + r) * NCHUNK + jc] =
                    dsum[a][r];
    }
}

// ---------------------------------------------------------------------------
// Kernel 3 (R13-verbatim): finalize. 128 blocks x 4 waves; each wave 8 rows.
// Per row: denom = sum(32 partials) - exp(selfdot);
// psum = <g_i, S[lab]> - selfdot; loss = log(denom) - psum/npos.
// Block reduce -> atomicAdd(out, mean part).
// ---------------------------------------------------------------------------
__global__ __launch_bounds__(256) void fin_kernel(
    const unsigned char* __restrict__ G8, const float* __restrict__ part_d,
    const float* __restrict__ S, const int* __restrict__ labels,
    const int* __restrict__ hist, float* __restrict__ out)
{
    const int tid  = threadIdx.x;
    const int wave = tid >> 6;
    const int lane = tid & 63;

    float lsum = 0.f;
    #pragma unroll 2
    for (int rr = 0; rr < 8; ++rr) {
        const int i   = (blockIdx.x * 4 + wave) * 8 + rr;
        const int lab = labels[i];
        float pd = (lane < NCHUNK) ? part_d[(size_t)i * NCHUNK + lane] : 0.f;
        const unsigned char* gr = G8 + (size_t)i * D_K + lane * 2;
        const float f0 = fp8_to_f32(gr[0]);
        const float f1 = fp8_to_f32(gr[1]);
        float2 sv = *reinterpret_cast<const float2*>(S + lab * D_K + lane * 2);
        float self = f0 * f0 + f1 * f1;
        float sp   = f0 * sv.x + f1 * sv.y;
        #pragma unroll
        for (int m = 1; m < 64; m <<= 1) {
            pd   += __shfl_xor(pd, m, 64);
            self += __shfl_xor(self, m, 64);
            sp   += __shfl_xor(sp, m, 64);
        }
        if (lane == 0) {
            const float npos  = (float)(hist[lab] - 1);
            const float denom = pd - __expf(self);
            lsum += __logf(denom) - (sp - self) / npos;
        }
    }
    __shared__ float w4[4];
    if (lane == 0) w4[wave] = lsum;
    __syncthreads();
    if (tid == 0)
        atomicAdd(out, (w4[0] + w4[1] + w4[2] + w4[3]) * (1.0f / (float)B_ROWS));
}

// ---------------------------------------------------------------------------
extern "C" void kernel_launch(void* const* d_in, const int* in_sizes, int n_in,
                              void* d_out, int out_size, void* d_ws, size_t ws_size,
                              hipStream_t stream) {
    const float* f      = (const float*)d_in[0];
    const float* fneg   = (const float*)d_in[1];
    const int*   labels = (const int*)d_in[2];
    float*       out    = (float*)d_out;

    char* ws = (char*)d_ws;
    // Workspace layout (bytes):
    //   G8     : 12288*128   = 1,572,864
    //   A8     : 4096*128    =   524,288
    //   part_d : 4096*32*4   =   524,288
    //   S      : 16*128*4    =     8,192
    //   hist   : 16*4
    unsigned char* G8     = (unsigned char*)(ws);
    unsigned char* A8     = (unsigned char*)(ws + 1572864);
    float*         part_d = (float*)(ws + 1572864 + 524288);
    float*         S      = (float*)(ws + 1572864 + 524288 + 524288);
    int*           hist   = (int*)(ws + 1572864 + 524288 + 524288 + 8192);

    nrm_kernel<<<N_TOT / 4, 256, 0, stream>>>(f, fneg, G8, A8, S, hist, out);

    dim3 gridS(NCHUNK, 36);   // (32,36): 1024 sim blocks + 128 csum svc blocks
    sim_kernel<<<gridS, 256, 0, stream>>>(G8, A8, labels, part_d, S, hist);

    fin_kernel<<<128, 256, 0, stream>>>(G8, part_d, S, labels, hist, out);
}

// Round 17
// 36.114 us; speedup vs baseline: 2.1193x; 1.0255x over previous
//
#include <hip/hip_runtime.h>
#include <hip/hip_bf16.h>
#include <hip/hip_fp8.h>

// Problem constants (fixed by setup_inputs): B=4096, d=128, M=8192, C=16
#define B_ROWS 4096
#define D_K    128
#define M_ROWS 8192
#define N_TOT  12288   // B_ROWS + M_ROWS
#define NCHUNK 32      // j-chunks (grid.x of sim), 384 cols each
#define JT_PER_CHUNK 6 // 6 tiles of 64 cols: 32*6*64 = 12288 = N_TOT (coverage!)
#define JCOLS  64      // cols per tile
#define NCLS   16

typedef __attribute__((ext_vector_type(4))) int   intx4;
typedef __attribute__((ext_vector_type(8))) int   intx8;
typedef __attribute__((ext_vector_type(4))) float floatx4;

__device__ __forceinline__ float fp8_to_f32(unsigned char b) {
    __hip_fp8_e4m3 h; h.__x = b; return float(h);
}

// ---------------------------------------------------------------------------
// Kernel 1 (R16-verbatim): normalize rows of f / f_neg into OCP fp8-e4m3
// G8[N_TOT][128]; in-batch rows additionally stored pre-scaled by log2(e)
// into A8 (sim A operand -> exp2 epilogue). One wave per row. Block 0 zeros
// S/hist/out.
// ---------------------------------------------------------------------------
__global__ __launch_bounds__(256) void nrm_kernel(
    const float* __restrict__ f, const float* __restrict__ fneg,
    unsigned char* __restrict__ G8, unsigned char* __restrict__ A8,
    float* __restrict__ S, int* __restrict__ hist, float* __restrict__ out)
{
    const int tid  = threadIdx.x;
    const int wave = tid >> 6;
    const int lane = tid & 63;
    const int row  = blockIdx.x * 4 + wave;           // grid exact: 3072*4
    if (blockIdx.x == 0) {
        #pragma unroll
        for (int k = 0; k < 8; ++k) S[tid + k * 256] = 0.f;
        if (tid < NCLS) hist[tid] = 0;
        if (tid == 0) out[0] = 0.f;
    }
    const float* src = (row < B_ROWS) ? (f + (size_t)row * D_K)
                                      : (fneg + (size_t)(row - B_ROWS) * D_K);
    float2 v = *reinterpret_cast<const float2*>(src + lane * 2);
    float ss = v.x * v.x + v.y * v.y;
    #pragma unroll
    for (int m = 1; m < 64; m <<= 1) ss += __shfl_xor(ss, m, 64);
    const float scale = 1.0f / fmaxf(sqrtf(ss), 1e-8f);   // 1/max(||x||, EPS)
    __hip_fp8_e4m3 q0(v.x * scale);
    __hip_fp8_e4m3 q1(v.y * scale);
    const unsigned short pk =
        (unsigned short)q0.__x | ((unsigned short)q1.__x << 8);
    *reinterpret_cast<unsigned short*>(G8 + (size_t)row * D_K + lane * 2) = pk;
    if (row < B_ROWS) {
        const float s2 = scale * 1.44269504f;             // * log2(e)
        __hip_fp8_e4m3 a0(v.x * s2);
        __hip_fp8_e4m3 a1(v.y * s2);
        const unsigned short pa =
            (unsigned short)a0.__x | ((unsigned short)a1.__x << 8);
        *reinterpret_cast<unsigned short*>(A8 + (size_t)row * D_K + lane * 2) = pa;
    }
}

// ---------------------------------------------------------------------------
// Kernel 2 (R16 + spill fix): sim + csum service blocks.
// ONLY change vs R16: __launch_bounds__(256, 2) — the old (256,4) made the
// allocator squeeze to 48 VGPRs (< the ~75+ live regs this body needs:
// afr 16 + acc 32 + dsum 8 + streg 8 + addr) -> inner-loop scratch spills,
// L2-contained so invisible in HBM counters but ~200cyc VMEM per spill op.
// (256,2) caps at 256; body needs ~90-120 -> expect <=128 -> still 4
// waves/SIMD, now spill-free.
// Grid (32, 36): y<32 sim (1024 blocks), y>=32 csum svc (128 blocks).
// ---------------------------------------------------------------------------
__global__ __launch_bounds__(256, 2) void sim_kernel(
    const unsigned char* __restrict__ G8, const unsigned char* __restrict__ A8,
    const int* __restrict__ labels, float* __restrict__ part_d,
    float* __restrict__ S, int* __restrict__ hist)
{
    __shared__ unsigned char Bs[2][JCOLS * D_K];   // 2 x 8KB

    const int tid = threadIdx.x;

    if (blockIdx.y >= 32) {        // ---- csum service blocks (R13-verbatim) ----
        const int svc    = (blockIdx.y - 32) * NCHUNK + blockIdx.x;  // 0..127
        const int stripe = svc & 31;   // 128-row stripe
        const int dc     = svc >> 5;   // 0..3 : 32-dim chunk
        float* Sp = (float*)&Bs[0][0];            // 2KB of the 16KB Bs
        int*   lh = (int*)(Sp + NCLS * 32);       // +64B
        for (int k = tid; k < NCLS * 32; k += 256) Sp[k] = 0.f;
        if (tid < NCLS) lh[tid] = 0;
        __syncthreads();

        const int j0 = stripe * 128;
        if (dc == 0 && tid < 128) atomicAdd(&lh[labels[j0 + tid]], 1);

        const int d = tid & 31;
        const int w = tid >> 5;               // 0..7 row-walkers
        for (int jj = w; jj < 128; jj += 8) {
            const int j = j0 + jj;
            const int c = labels[j];
            atomicAdd(&Sp[c * 32 + d],
                      fp8_to_f32(G8[(size_t)j * D_K + dc * 32 + d]));
        }
        __syncthreads();
        for (int k = tid; k < NCLS * 32; k += 256)
            atomicAdd(&S[(k >> 5) * D_K + dc * 32 + (k & 31)], Sp[k]);
        if (dc == 0 && tid < NCLS) atomicAdd(&hist[tid], lh[tid]);
        return;
    }

    const int jc   = blockIdx.x;          // 0..31
    const int it   = blockIdx.y;          // 0..31
    const int wave = tid >> 6;            // 0..3 : i-quarter
    const int lane = tid & 63;
    const int i0   = it * 128 + wave * 32;

    const int r16 = lane & 15;
    const int grp = lane >> 4;            // 0..3

    // resident A fragments [a] from A8 (log2e-scaled): rows i0 + a*16 + r16
    const unsigned char* Abase = A8 + (size_t)(i0 + r16) * D_K + grp * 32;
    intx8 afr[2];
    #pragma unroll
    for (int a = 0; a < 2; ++a)
        afr[a] = *reinterpret_cast<const intx8*>(Abase + (size_t)a * 16 * D_K);

    float dsum[2][4];
    #pragma unroll
    for (int a = 0; a < 2; ++a)
        #pragma unroll
        for (int r = 0; r < 4; ++r) dsum[a][r] = 0.f;

    // staging: 8KB tile, 256 thr x 16B x 2 rounds. LDS linear byte
    // p = s*4096 + tid*16 -> row = s*32 + tid/8, slot = tid&7;
    // source granule pre-swizzled: gran = slot ^ ((row>>2)&1)
    int srcoff[2];
    #pragma unroll
    for (int s = 0; s < 2; ++s) {
        const int row  = s * 32 + (tid >> 3);
        const int gran = (tid & 7) ^ ((row >> 2) & 1);
        srcoff[s] = row * D_K + gran * 16;
    }

    intx4 streg[2];
    {   // prologue: tile 0 -> buf 0
        const unsigned char* src =
            G8 + (size_t)(jc * JT_PER_CHUNK) * JCOLS * D_K;
        #pragma unroll
        for (int s = 0; s < 2; ++s)
            streg[s] = *reinterpret_cast<const intx4*>(src + srcoff[s]);
        #pragma unroll
        for (int s = 0; s < 2; ++s)
            *reinterpret_cast<intx4*>(&Bs[0][0] + s * 4096 + tid * 16) =
                streg[s];
    }

    for (int t = 0; t < JT_PER_CHUNK; ++t) {
        const int cur = t & 1;
        __syncthreads();   // buf[cur] written & visible; buf[cur^1] reads done

        if (t + 1 < JT_PER_CHUNK) {
            const unsigned char* src =
                G8 + (size_t)(jc * JT_PER_CHUNK + t + 1) * JCOLS * D_K;
            #pragma unroll
            for (int s = 0; s < 2; ++s)
                streg[s] = *reinterpret_cast<const intx4*>(src + srcoff[s]);
        }

        floatx4 acc[2][4];
        #pragma unroll
        for (int a = 0; a < 2; ++a)
            #pragma unroll
            for (int b = 0; b < 4; ++b)
                acc[a][b] = (floatx4){0.f, 0.f, 0.f, 0.f};

        const unsigned char* base = &Bs[cur][0];
        #pragma unroll
        for (int b = 0; b < 4; ++b) {
            const int jloc = b * 16 + r16;
            const int sw   = (jloc >> 2) & 1;            // row bit 2
            intx4 lo = *reinterpret_cast<const intx4*>(
                base + jloc * D_K + ((2 * grp)     ^ sw) * 16);
            intx4 hi = *reinterpret_cast<const intx4*>(
                base + jloc * D_K + ((2 * grp + 1) ^ sw) * 16);
            intx8 bfr;
            // sw only flips granule bit0: lo/hi swap when sw==1.
            if (sw) { intx4 tmp = lo; lo = hi; hi = tmp; }
            #pragma unroll
            for (int e = 0; e < 4; ++e) { bfr[e] = lo[e]; bfr[e + 4] = hi[e]; }
            #pragma unroll
            for (int a = 0; a < 2; ++a)
                acc[a][b] = __builtin_amdgcn_mfma_scale_f32_16x16x128_f8f6f4(
                    afr[a], bfr, acc[a][b], 0, 0,
                    0, 0x7F7F7F7F, 0, 0x7F7F7F7F);   // unity scales
        }

        // branch-free epilogue: acc = log2e*sim -> exp2 (native v_exp_f32)
        #pragma unroll
        for (int a = 0; a < 2; ++a)
            #pragma unroll
            for (int r = 0; r < 4; ++r) {
                float s0 = exp2f(acc[a][0][r]) + exp2f(acc[a][1][r]);
                float s1 = exp2f(acc[a][2][r]) + exp2f(acc[a][3][r]);
                dsum[a][r] += s0 + s1;
            }

        if (t + 1 < JT_PER_CHUNK) {
            #pragma unroll
            for (int s = 0; s < 2; ++s)
                *reinterpret_cast<intx4*>(
                    &Bs[cur ^ 1][0] + s * 4096 + tid * 16) = streg[s];
        }
    }

    // 16-lane (column-group) reduce
    #pragma unroll
    for (int a = 0; a < 2; ++a)
        #pragma unroll
        for (int r = 0; r < 4; ++r) {
            #pragma unroll
            for (int m = 1; m < 16; m <<= 1)
                dsum[a][r] += __shfl_xor(dsum[a][r], m, 64);
        }
    if (r16 == 0) {
        #pragma unroll
        for (int a = 0; a < 2; ++a)
            #pragma unroll
            for (int r = 0; r < 4; ++r)
                part_d[(size_t)(i0 + a * 16 + grp * 4 + r) * NCHUNK + jc] =
                    dsum[a][r];
    }
}

// ---------------------------------------------------------------------------
// Kernel 3 (R16-verbatim): finalize. 128 blocks x 4 waves; each wave 8 rows.
// Per row: denom = sum(32 partials) - exp(selfdot);
// psum = <g_i, S[lab]> - selfdot; loss = log(denom) - psum/npos.
// Block reduce -> atomicAdd(out, mean part).
// ---------------------------------------------------------------------------
__global__ __launch_bounds__(256) void fin_kernel(
    const unsigned char* __restrict__ G8, const float* __restrict__ part_d,
    const float* __restrict__ S, const int* __restrict__ labels,
    const int* __restrict__ hist, float* __restrict__ out)
{
    const int tid  = threadIdx.x;
    const int wave = tid >> 6;
    const int lane = tid & 63;

    float lsum = 0.f;
    #pragma unroll 2
    for (int rr = 0; rr < 8; ++rr) {
        const int i   = (blockIdx.x * 4 + wave) * 8 + rr;
        const int lab = labels[i];
        float pd = (lane < NCHUNK) ? part_d[(size_t)i * NCHUNK + lane] : 0.f;
        const unsigned char* gr = G8 + (size_t)i * D_K + lane * 2;
        const float f0 = fp8_to_f32(gr[0]);
        const float f1 = fp8_to_f32(gr[1]);
        float2 sv = *reinterpret_cast<const float2*>(S + lab * D_K + lane * 2);
        float self = f0 * f0 + f1 * f1;
        float sp   = f0 * sv.x + f1 * sv.y;
        #pragma unroll
        for (int m = 1; m < 64; m <<= 1) {
            pd   += __shfl_xor(pd, m, 64);
            self += __shfl_xor(self, m, 64);
            sp   += __shfl_xor(sp, m, 64);
        }
        if (lane == 0) {
            const float npos  = (float)(hist[lab] - 1);
            const float denom = pd - __expf(self);
            lsum += __logf(denom) - (sp - self) / npos;
        }
    }
    __shared__ float w4[4];
    if (lane == 0) w4[wave] = lsum;
    __syncthreads();
    if (tid == 0)
        atomicAdd(out, (w4[0] + w4[1] + w4[2] + w4[3]) * (1.0f / (float)B_ROWS));
}

// ---------------------------------------------------------------------------
extern "C" void kernel_launch(void* const* d_in, const int* in_sizes, int n_in,
                              void* d_out, int out_size, void* d_ws, size_t ws_size,
                              hipStream_t stream) {
    const float* f      = (const float*)d_in[0];
    const float* fneg   = (const float*)d_in[1];
    const int*   labels = (const int*)d_in[2];
    float*       out    = (float*)d_out;

    char* ws = (char*)d_ws;
    // Workspace layout (bytes):
    //   G8     : 12288*128   = 1,572,864
    //   A8     : 4096*128    =   524,288
    //   part_d : 4096*32*4   =   524,288
    //   S      : 16*128*4    =     8,192
    //   hist   : 16*4
    unsigned char* G8     = (unsigned char*)(ws);
    unsigned char* A8     = (unsigned char*)(ws + 1572864);
    float*         part_d = (float*)(ws + 1572864 + 524288);
    float*         S      = (float*)(ws + 1572864 + 524288 + 524288);
    int*           hist   = (int*)(ws + 1572864 + 524288 + 524288 + 8192);

    nrm_kernel<<<N_TOT / 4, 256, 0, stream>>>(f, fneg, G8, A8, S, hist, out);

    dim3 gridS(NCHUNK, 36);   // (32,36): 1024 sim blocks + 128 csum svc blocks
    sim_kernel<<<gridS, 256, 0, stream>>>(G8, A8, labels, part_d, S, hist);

    fin_kernel<<<128, 256, 0, stream>>>(G8, part_d, S, labels, hist, out);
}